// Round 1
// baseline (41148.166 us; speedup 1.0000x reference)
//
#include <hip/hip_runtime.h>
#include <hip/hip_bf16.h>
#include <hip/hip_cooperative_groups.h>

namespace cg = cooperative_groups;

#define B_  32
#define TS_ 64
#define TD_ 63
#define E_  256
#define U_  1024
#define G_  4096   // 4*U
#define VT_ 32000

typedef __attribute__((ext_vector_type(8))) short short8;
typedef __attribute__((ext_vector_type(4))) float floatx4;

__device__ __forceinline__ float sigf(float x){ return 1.0f/(1.0f+__expf(-x)); }
__device__ __forceinline__ float tanh_fast(float x){ return 2.0f/(1.0f+__expf(-2.0f*x)) - 1.0f; }
__device__ __forceinline__ unsigned short f2bf(float x){
  unsigned u = __float_as_uint(x);
  u += 0x7FFFu + ((u>>16)&1u);
  return (unsigned short)(u>>16);
}

// ---------------- zero init ----------------
__global__ void zero_kernel(float4* __restrict__ p, int n4){
  int i = blockIdx.x*256 + threadIdx.x;
  if(i < n4) p[i] = make_float4(0.f,0.f,0.f,0.f);
}

// ---------------- generic row-gather GEMM (fp32) ----------------
__global__ __launch_bounds__(256) void gemm_rows(
    const float* __restrict__ Atab, const int* __restrict__ tokens, int T,
    const float* __restrict__ Bw, const float* __restrict__ bias,
    float* __restrict__ C, int N, int K)
{
  __shared__ float as[64*20];
  int tid = threadIdx.x;
  int n  = blockIdx.x*256 + tid;
  int m0 = blockIdx.y*16;
  float acc[16];
  #pragma unroll
  for(int r=0;r<16;r++) acc[r]=0.f;

  for(int kc=0; kc<K; kc+=64){
    __syncthreads();
    for(int i=tid; i<16*64; i+=256){
      int mm = i>>6, kk = i&63;
      int m = m0 + mm;
      const float* arow;
      if(tokens){
        int b = m & 31, t = m >> 5;
        arow = Atab + (size_t)tokens[b*T + t]*K;
      } else {
        arow = Atab + (size_t)m*K;
      }
      as[kk*20 + mm] = arow[kc + kk];
    }
    __syncthreads();
    for(int kk=0; kk<64; kk++){
      float bv = Bw[(size_t)(kc+kk)*N + n];
      const float4* ap = (const float4*)(as + kk*20);
      float4 a0 = ap[0], a1 = ap[1], a2 = ap[2], a3 = ap[3];
      acc[0]  += a0.x*bv; acc[1]  += a0.y*bv; acc[2]  += a0.z*bv; acc[3]  += a0.w*bv;
      acc[4]  += a1.x*bv; acc[5]  += a1.y*bv; acc[6]  += a1.z*bv; acc[7]  += a1.w*bv;
      acc[8]  += a2.x*bv; acc[9]  += a2.y*bv; acc[10] += a2.z*bv; acc[11] += a2.w*bv;
      acc[12] += a3.x*bv; acc[13] += a3.y*bv; acc[14] += a3.z*bv; acc[15] += a3.w*bv;
    }
  }
  float bv = bias ? bias[n] : 0.f;
  #pragma unroll
  for(int r=0;r<16;r++)
    C[(size_t)(m0+r)*N + n] = acc[r] + bv;
}

// ---------------- (fallback) recurrent-step split-K GEMM ----------------
__global__ __launch_bounds__(256) void step_mm(
    const float* __restrict__ W1, const float* __restrict__ W2,
    const float* __restrict__ s1, const float* __restrict__ s2,
    float* __restrict__ zpart, int N)
{
  int tid = threadIdx.x;
  int nl = tid & 63, mg = tid >> 6;
  int n = blockIdx.x*64 + nl;
  int kq = blockIdx.y;
  int k0 = (kq & 3) * 256;
  const float* W  = ((kq < 4) ? W1 : W2) + (size_t)k0 * N + n;
  const float* hp = ((kq < 4) ? s1 : s2) + (size_t)(mg*8) * U_ + k0;
  float acc[8];
  #pragma unroll
  for(int i=0;i<8;i++) acc[i]=0.f;
  #pragma unroll 4
  for(int k=0; k<256; k++){
    float wv = W[(size_t)k * N];
    #pragma unroll
    for(int mi=0; mi<8; mi++)
      acc[mi] += hp[(size_t)mi*U_ + k] * wv;
  }
  float* zp = zpart + ((size_t)(kq*32 + mg*8)) * N + n;
  #pragma unroll
  for(int mi=0; mi<8; mi++)
    zp[(size_t)mi * N] = acc[mi];
}

// ---------------- (fallback) gates ----------------
__global__ __launch_bounds__(256) void gate_h(
    const float* __restrict__ X_t, const float* __restrict__ zpart, int KQ,
    float* __restrict__ c, float* __restrict__ hout)
{
  int i = blockIdx.x*256 + threadIdx.x;   // 0..32767
  int b = i >> 10, u = i & 1023;
  float zg[4];
  #pragma unroll
  for(int g=0; g<4; g++){
    int col = g*U_ + u;
    float s = X_t[(size_t)b*G_ + col];
    for(int p=0; p<KQ; p++) s += zpart[((size_t)(p*32+b))*G_ + col];
    zg[g] = s;
  }
  float cn = sigf(zg[1])*c[i] + sigf(zg[0])*tanh_fast(zg[2]);
  float hn = sigf(zg[3])*tanh_fast(cn);
  c[i] = cn;
  hout[i] = hn;
}

// ---------------- (fallback) decoder gates+attention ----------------
__global__ __launch_bounds__(256) void dec_gate_attn(
    const float* __restrict__ Xd_t, const float* __restrict__ zpart,
    float* __restrict__ c, const float* __restrict__ keys,
    const float* __restrict__ memory, float* __restrict__ hout,
    float* __restrict__ ctx)
{
  int b = blockIdx.x;
  int tid = threadIdx.x;
  __shared__ float hs[1024];
  __shared__ float sc[64];
  __shared__ float al[64];
  #pragma unroll
  for(int uu=0; uu<4; uu++){
    int u = uu*256 + tid;
    float zg[4];
    #pragma unroll
    for(int g=0; g<4; g++){
      int col = g*U_ + u;
      float s = Xd_t[(size_t)b*G_ + col];
      #pragma unroll
      for(int p=0; p<8; p++) s += zpart[((size_t)(p*32+b))*G_ + col];
      zg[g] = s;
    }
    int ci = b*U_ + u;
    float cn = sigf(zg[1])*c[ci] + sigf(zg[0])*tanh_fast(zg[2]);
    float hn = sigf(zg[3])*tanh_fast(cn);
    c[ci] = cn;
    hs[u] = hn;
    hout[ci] = hn;
  }
  __syncthreads();
  int w = tid>>6, lane = tid&63;
  for(int si=0; si<16; si++){
    int s = w*16 + si;
    const float* kr = keys + ((size_t)s*B_ + b)*U_;
    float p = 0.f;
    for(int kk=lane; kk<1024; kk+=64) p += hs[kk]*kr[kk];
    for(int off=32; off; off>>=1) p += __shfl_down(p, off);
    if(lane==0) sc[s] = p;
  }
  __syncthreads();
  if(tid<64){
    float v = sc[tid];
    float mx = v;
    for(int off=32; off; off>>=1) mx = fmaxf(mx, __shfl_down(mx, off));
    mx = __shfl(mx, 0);
    float e = __expf(v - mx);
    float sm = e;
    for(int off=32; off; off>>=1) sm += __shfl_down(sm, off);
    sm = __shfl(sm, 0);
    al[tid] = e/sm;
  }
  __syncthreads();
  #pragma unroll
  for(int uu=0; uu<4; uu++){
    int u = uu*256 + tid;
    float a = 0.f;
    for(int s=0; s<64; s++) a += al[s]*memory[((size_t)s*B_ + b)*U_ + u];
    ctx[b*U_ + u] = a;
  }
}

// ---------------- (fallback) attention-projection combine ----------------
__global__ __launch_bounds__(256) void attn_combine(
    const float* __restrict__ apart, float* __restrict__ attn_next,
    unsigned short* __restrict__ abf)
{
  int i = blockIdx.x*256 + threadIdx.x;   // 0..32767
  float s = 0.f;
  #pragma unroll
  for(int p=0; p<8; p++) s += apart[(size_t)p*32768 + i];
  attn_next[i] = s;
  abf[i] = f2bf(s);
}

// ================= persistent cooperative recurrence =================
// 256 blocks x 256 threads; phases separated by grid.sync().
// Encoder: E1 z-partials (block=(nb 0..63, kq 0..3)), E2 gates (32768 elems).
// Keys:   memory@Wm, block=(nb 0..15, rq 0..15), 4 row-groups of 32.
// Decoder: D1 z = h@Wh_d + a@Wxa fused per k-chunk (4 partials),
//          D2 per-batch gates+scores+softmax+ctx (blocks 0..31),
//          D3 attn=[h|ctx]@Wa split-K 16 (block=(nb 0..15, kq 0..15)),
//          D4 combine 16 partials + bf16 emit.
struct RecParams {
  const float* Xe; const float* Xd;
  const float* Wh_e; const float* Wh_d; const float* Wxa;
  const float* Wm; const float* Wa;
  float* memory; float* keys; float* attn_buf;
  float* cbuf; float* hbuf; float* ctx;
  float* zpart;          // 4 slots [32][4096]
  float* apart;          // 16 slots [32][1024] (aliases zpart slots 4..7)
  unsigned short* attn_bf;
};

__global__ __launch_bounds__(256) void seq_rnn(RecParams P)
{
  cg::grid_group grid = cg::this_grid();
  __shared__ float hs[1024];
  __shared__ float sc[64];
  __shared__ float al[64];
  const int bid  = blockIdx.x;
  const int tid  = threadIdx.x;
  const int lane = tid & 63;
  const int mg   = tid >> 6;

  // ---------------- encoder ----------------
  for(int t=0; t<TS_; ++t){
    { // E1: zpart[kq] = hprev @ Wh_e k-chunk
      const float* hprev = (t==0) ? P.attn_buf : P.memory + (size_t)(t-1)*B_*U_;
      const int nb = bid & 63, kq = bid >> 6;
      const int n = nb*64 + lane, k0 = kq*256;
      const float* W  = P.Wh_e + (size_t)k0*G_ + n;
      const float* hp = hprev + (size_t)(mg*8)*U_ + k0;
      float acc[8];
      #pragma unroll
      for(int i=0;i<8;i++) acc[i]=0.f;
      #pragma unroll 4
      for(int k=0;k<256;k++){
        float wv = W[(size_t)k*G_];
        #pragma unroll
        for(int mi=0;mi<8;mi++) acc[mi] += hp[(size_t)mi*U_+k]*wv;
      }
      float* zp = P.zpart + ((size_t)(kq*32+mg*8))*G_ + n;
      #pragma unroll
      for(int mi=0;mi<8;mi++) zp[(size_t)mi*G_] = acc[mi];
    }
    grid.sync();
    { // E2: gates (first 128 blocks, 1 elem/thread)
      const int gidx = bid*256 + tid;
      if(gidx < B_*U_){
        const int b = gidx>>10, u = gidx&1023;
        const float* Xt = P.Xe + (size_t)t*B_*G_ + (size_t)b*G_;
        float zg[4];
        #pragma unroll
        for(int g=0;g<4;g++){
          const int col = g*U_+u;
          float s = Xt[col];
          #pragma unroll
          for(int p=0;p<4;p++) s += P.zpart[((size_t)(p*32+b))*G_+col];
          zg[g]=s;
        }
        const float cn = sigf(zg[1])*P.cbuf[gidx] + sigf(zg[0])*tanh_fast(zg[2]);
        const float hn = sigf(zg[3])*tanh_fast(cn);
        P.cbuf[gidx]=cn;
        P.memory[(size_t)t*B_*U_+gidx]=hn;
      }
    }
    grid.sync();
  }

  // ---------------- keys = memory @ Wm ----------------
  {
    const int nb = bid & 15, rq = bid >> 4;
    const int n = nb*64 + lane;
    for(int rg=0; rg<4; rg++){
      const int r0 = rq*128 + rg*32 + mg*8;
      const float* src = P.memory + (size_t)r0*U_;
      float acc[8];
      #pragma unroll
      for(int i=0;i<8;i++) acc[i]=0.f;
      #pragma unroll 4
      for(int k=0;k<1024;k++){
        float wv = P.Wm[(size_t)k*U_ + n];
        #pragma unroll
        for(int mi=0;mi<8;mi++) acc[mi] += src[(size_t)mi*U_+k]*wv;
      }
      float* kp = P.keys + (size_t)r0*U_ + n;
      #pragma unroll
      for(int mi=0;mi<8;mi++) kp[(size_t)mi*U_] = acc[mi];
    }
  }
  grid.sync();

  // ---------------- decoder ----------------
  for(int t=0; t<TD_; ++t){
    const float* hin   = (t==0) ? (P.memory + (size_t)(TS_-1)*B_*U_) : P.hbuf;
    const float* aprev = P.attn_buf + (size_t)t*B_*U_;
    { // D1: zpart[kq] = hin@Wh_d chunk + aprev@Wxa chunk (fused)
      const int nb = bid & 63, kq = bid >> 6;
      const int n = nb*64 + lane, k0 = kq*256;
      float acc[8];
      #pragma unroll
      for(int i=0;i<8;i++) acc[i]=0.f;
      const float* W1 = P.Wh_d + (size_t)k0*G_ + n;
      const float* h1 = hin + (size_t)(mg*8)*U_ + k0;
      #pragma unroll 4
      for(int k=0;k<256;k++){
        float wv = W1[(size_t)k*G_];
        #pragma unroll
        for(int mi=0;mi<8;mi++) acc[mi] += h1[(size_t)mi*U_+k]*wv;
      }
      const float* W2 = P.Wxa + (size_t)k0*G_ + n;
      const float* h2 = aprev + (size_t)(mg*8)*U_ + k0;
      #pragma unroll 4
      for(int k=0;k<256;k++){
        float wv = W2[(size_t)k*G_];
        #pragma unroll
        for(int mi=0;mi<8;mi++) acc[mi] += h2[(size_t)mi*U_+k]*wv;
      }
      float* zp = P.zpart + ((size_t)(kq*32+mg*8))*G_ + n;
      #pragma unroll
      for(int mi=0;mi<8;mi++) zp[(size_t)mi*G_] = acc[mi];
    }
    grid.sync();
    // D2: gates + scores + softmax + context, one block per batch
    if(bid < B_){
      const int b = bid;
      const float* Xt = P.Xd + (size_t)t*B_*G_ + (size_t)b*G_;
      #pragma unroll
      for(int uu=0; uu<4; uu++){
        const int u = uu*256 + tid;
        float zg[4];
        #pragma unroll
        for(int g=0;g<4;g++){
          const int col = g*U_+u;
          float s = Xt[col];
          #pragma unroll
          for(int p=0;p<4;p++) s += P.zpart[((size_t)(p*32+b))*G_+col];
          zg[g]=s;
        }
        const int ci = b*U_+u;
        const float cn = sigf(zg[1])*P.cbuf[ci] + sigf(zg[0])*tanh_fast(zg[2]);
        const float hn = sigf(zg[3])*tanh_fast(cn);
        P.cbuf[ci]=cn; hs[u]=hn; P.hbuf[ci]=hn;
      }
      __syncthreads();
      const int w = tid>>6, ln = tid&63;
      for(int si=0; si<16; si++){
        const int s = w*16 + si;
        const float* kr = P.keys + ((size_t)s*B_ + b)*U_;
        float p = 0.f;
        for(int kk=ln; kk<1024; kk+=64) p += hs[kk]*kr[kk];
        #pragma unroll
        for(int off=32; off; off>>=1) p += __shfl_down(p, off);
        if(ln==0) sc[s] = p;
      }
      __syncthreads();
      if(tid<64){
        float v = sc[tid];
        float mx = v;
        #pragma unroll
        for(int off=32; off; off>>=1) mx = fmaxf(mx, __shfl_down(mx, off));
        mx = __shfl(mx, 0);
        float e = __expf(v - mx);
        float sm = e;
        #pragma unroll
        for(int off=32; off; off>>=1) sm += __shfl_down(sm, off);
        sm = __shfl(sm, 0);
        al[tid] = e/sm;
      }
      __syncthreads();
      #pragma unroll
      for(int uu=0; uu<4; uu++){
        const int u = uu*256 + tid;
        float a = 0.f;
        for(int s=0; s<64; s++) a += al[s]*P.memory[((size_t)s*B_ + b)*U_ + u];
        P.ctx[b*U_+u] = a;
      }
    }
    grid.sync();
    { // D3: apart[kq] = [h|ctx] chunk @ Wa chunk, split-K 16 x 128
      const int nb = bid & 15, kq = bid >> 4;
      const int n = nb*64 + lane;
      const float* W = P.Wa + (size_t)(kq*128)*U_ + n;
      const float* src = (kq < 8) ? (P.hbuf + (size_t)(mg*8)*U_ + kq*128)
                                  : (P.ctx  + (size_t)(mg*8)*U_ + (kq-8)*128);
      float acc[8];
      #pragma unroll
      for(int i=0;i<8;i++) acc[i]=0.f;
      #pragma unroll 4
      for(int k=0;k<128;k++){
        float wv = W[(size_t)k*U_];
        #pragma unroll
        for(int mi=0;mi<8;mi++) acc[mi] += src[(size_t)mi*U_+k]*wv;
      }
      float* ap = P.apart + ((size_t)(kq*32+mg*8))*U_ + n;
      #pragma unroll
      for(int mi=0;mi<8;mi++) ap[(size_t)mi*U_] = acc[mi];
    }
    grid.sync();
    { // D4: combine 16 partials, write attn_next + bf16
      const int gidx = bid*256 + tid;
      if(gidx < B_*U_){
        float s = 0.f;
        #pragma unroll
        for(int p=0;p<16;p++) s += P.apart[(size_t)p*B_*U_ + gidx];
        P.attn_buf[(size_t)(t+1)*B_*U_ + gidx] = s;
        P.attn_bf[(size_t)t*B_*U_ + gidx] = f2bf(s);
      }
    }
    grid.sync();
  }
}

// ---------------- Wf transpose to bf16 ----------------
__global__ __launch_bounds__(256) void transpose_f2bf(
    const float* __restrict__ Wf, unsigned short* __restrict__ WfT)
{
  __shared__ float t[32][33];
  int n0 = blockIdx.x*32, k0 = blockIdx.y*32;
  int tid = threadIdx.x;
  int cx = tid&31, ry = tid>>5;
  for(int r=ry; r<32; r+=8) t[r][cx] = Wf[(size_t)(k0+r)*VT_ + n0+cx];
  __syncthreads();
  for(int r=ry; r<32; r+=8)
    WfT[(size_t)(n0+r)*1024 + k0+cx] = f2bf(t[cx][r]);
}

// ---------------- logits GEMM: bf16 MFMA 16x16x32 ----------------
__global__ __launch_bounds__(256) void logits_gemm(
    const unsigned short* __restrict__ Abf, const unsigned short* __restrict__ Bt,
    const float* __restrict__ bias, float* __restrict__ out)
{
  __shared__ __align__(16) unsigned short As[32][40];
  __shared__ __align__(16) unsigned short Bs[256][40];
  int tid = threadIdx.x;
  int m0 = blockIdx.x*32, n0 = blockIdx.y*256;
  int w = tid>>6, lane = tid&63;
  int wm = w&1, wn = w>>1;
  floatx4 acc[8];
  #pragma unroll
  for(int i=0;i<8;i++) acc[i] = (floatx4)(0.f);

  int rl = lane&15, kg = lane>>4;

  for(int kt=0; kt<1024; kt+=32){
    __syncthreads();
    {
      int mm = tid>>3, kq = tid&7;
      const unsigned short* src = Abf + (size_t)(m0+mm)*1024 + kt + kq*4;
      *(uint2*)(&As[mm][kq*4]) = *(const uint2*)src;
    }
    {
      const unsigned short* bsrc = Bt + (size_t)(n0+tid)*1024 + kt;
      *(uint4*)(&Bs[tid][0])  = *(const uint4*)(bsrc);
      *(uint4*)(&Bs[tid][8])  = *(const uint4*)(bsrc+8);
      *(uint4*)(&Bs[tid][16]) = *(const uint4*)(bsrc+16);
      *(uint4*)(&Bs[tid][24]) = *(const uint4*)(bsrc+24);
    }
    __syncthreads();
    short8 afrag = *(const short8*)(&As[wm*16 + rl][kg*8]);
    #pragma unroll
    for(int nt=0; nt<8; nt++){
      short8 bfrag = *(const short8*)(&Bs[wn*128 + nt*16 + rl][kg*8]);
      acc[nt] = __builtin_amdgcn_mfma_f32_16x16x32_bf16(afrag, bfrag, acc[nt], 0,0,0);
    }
  }
  #pragma unroll
  for(int nt=0; nt<8; nt++){
    int n = n0 + wn*128 + nt*16 + rl;
    float bv = bias[n];
    #pragma unroll
    for(int r=0;r<4;r++){
      int m = m0 + wm*16 + kg*4 + r;
      int t = m>>5, b = m&31;
      out[((size_t)(b*TD_) + t)*VT_ + n] = acc[nt][r] + bv;
    }
  }
}

// ---------------- host ----------------
extern "C" void kernel_launch(void* const* d_in, const int* in_sizes, int n_in,
                              void* d_out, int out_size, void* d_ws, size_t ws_size,
                              hipStream_t stream) {
  (void)in_sizes; (void)n_in; (void)out_size; (void)ws_size;
  const int*   enc_in  = (const int*)d_in[0];
  const int*   dec_in  = (const int*)d_in[1];
  const float* enc_emb = (const float*)d_in[2];
  const float* dec_emb = (const float*)d_in[3];
  const float* Wx_e    = (const float*)d_in[4];
  const float* Wh_e    = (const float*)d_in[5];
  const float* b_e     = (const float*)d_in[6];
  const float* Wx_d    = (const float*)d_in[7];
  const float* Wh_d    = (const float*)d_in[8];
  const float* b_d     = (const float*)d_in[9];
  const float* Wm      = (const float*)d_in[10];
  const float* Wa      = (const float*)d_in[11];
  const float* Wf      = (const float*)d_in[12];
  const float* bf      = (const float*)d_in[13];
  float* out = (float*)d_out;

  float* ws = (float*)d_ws;
  size_t off = 0;
  float* Xe       = ws + off; off += (size_t)TS_*B_*G_;
  float* Xd       = ws + off; off += (size_t)TD_*B_*G_;
  float* memory   = ws + off; off += (size_t)TS_*B_*U_;
  float* keys     = ws + off; off += (size_t)TS_*B_*U_;
  float* attn_buf = ws + off; off += (size_t)64*B_*U_;      // slot0 = zeros
  float* cbuf     = ws + off; off += (size_t)B_*U_;
  float* hbuf     = ws + off; off += (size_t)B_*U_;
  float* ctx      = ws + off; off += (size_t)B_*U_;
  float* zpart    = ws + off; off += (size_t)8*B_*G_;       // slots 0..3 = z partials, 4..7 = attn partials (coop)
  float* apart    = ws + off; off += (size_t)8*B_*U_;       // fallback-only
  unsigned short* attn_bf = (unsigned short*)(ws + off); off += (size_t)(2016*1024)/2;
  unsigned short* WfT     = (unsigned short*)(ws + off);

  // zero attn slot0 + cbuf
  zero_kernel<<<32, 256, 0, stream>>>((float4*)attn_buf, (B_*U_)/4);
  zero_kernel<<<32, 256, 0, stream>>>((float4*)cbuf, (B_*U_)/4);

  // input pre-activations + Wf transpose (off the critical recurrence)
  gemm_rows<<<dim3(G_/256, (TS_*B_)/16), 256, 0, stream>>>(enc_emb, enc_in, TS_, Wx_e, b_e, Xe, G_, E_);
  gemm_rows<<<dim3(G_/256, (TD_*B_)/16), 256, 0, stream>>>(dec_emb, dec_in, TD_, Wx_d, b_d, Xd, G_, E_);
  transpose_f2bf<<<dim3(VT_/32, 1024/32), 256, 0, stream>>>(Wf, WfT);

  const float* Wxa = Wx_d + (size_t)E_*G_;

  // ---- persistent cooperative recurrence (encoder + keys + decoder) ----
  RecParams P;
  P.Xe = Xe; P.Xd = Xd;
  P.Wh_e = Wh_e; P.Wh_d = Wh_d; P.Wxa = Wxa;
  P.Wm = Wm; P.Wa = Wa;
  P.memory = memory; P.keys = keys; P.attn_buf = attn_buf;
  P.cbuf = cbuf; P.hbuf = hbuf; P.ctx = ctx;
  P.zpart = zpart;
  P.apart = zpart + (size_t)4*B_*G_;   // alias slots 4..7 (16 x [32][1024])
  P.attn_bf = attn_bf;
  void* kargs[1] = { (void*)&P };
  hipError_t ce = hipLaunchCooperativeKernel(seq_rnn, dim3(256), dim3(256),
                                             kargs, 0u, stream);

  if(ce != hipSuccess){
    // -------- fallback: previous per-step launch sequence --------
    for(int t=0; t<TS_; t++){
      const float* hprev = (t==0) ? attn_buf : memory + (size_t)(t-1)*B_*U_;
      step_mm<<<dim3(G_/64, 4), 256, 0, stream>>>(Wh_e, Wh_e, hprev, hprev, zpart, G_);
      gate_h<<<128, 256, 0, stream>>>(Xe + (size_t)t*B_*G_, zpart, 4, cbuf,
                                      memory + (size_t)t*B_*U_);
    }
    gemm_rows<<<dim3(U_/256, (TS_*B_)/16), 256, 0, stream>>>(memory, nullptr, 0, Wm, nullptr, keys, U_, U_);
    const float* mem_last = memory + (size_t)(TS_-1)*B_*U_;
    const float* Wa2 = Wa + (size_t)U_*U_;
    for(int t=0; t<TD_; t++){
      const float* hin   = (t==0) ? mem_last : hbuf;
      const float* aprev = attn_buf + (size_t)t*B_*U_;
      float* anext       = attn_buf + (size_t)(t+1)*B_*U_;
      step_mm<<<dim3(G_/64, 8), 256, 0, stream>>>(Wh_d, Wxa, hin, aprev, zpart, G_);
      dec_gate_attn<<<B_, 256, 0, stream>>>(Xd + (size_t)t*B_*G_, zpart, cbuf,
                                            keys, memory, hbuf, ctx);
      step_mm<<<dim3(U_/64, 8), 256, 0, stream>>>(Wa, Wa2, hbuf, ctx, apart, U_);
      attn_combine<<<128, 256, 0, stream>>>(apart, anext, attn_bf + (size_t)t*B_*U_);
    }
  }

  // logits = attn_all @ Wf + bf  (bf16 MFMA)
  logits_gemm<<<dim3((TD_*B_)/32, VT_/256), 256, 0, stream>>>(attn_bf, WfT, bf, out);
}

// Round 2
// 16005.688 us; speedup vs baseline: 2.5708x; 2.5708x over previous
//
#include <hip/hip_runtime.h>
#include <hip/hip_bf16.h>

#define B_  32
#define TS_ 64
#define TD_ 63
#define E_  256
#define U_  1024
#define G_  4096   // 4*U
#define VT_ 32000

typedef __attribute__((ext_vector_type(8))) short short8;
typedef __attribute__((ext_vector_type(4))) float floatx4;

__device__ __forceinline__ float sigf(float x){ return 1.0f/(1.0f+__expf(-x)); }
__device__ __forceinline__ float tanh_fast(float x){ return 2.0f/(1.0f+__expf(-2.0f*x)) - 1.0f; }
__device__ __forceinline__ unsigned short f2bf(float x){
  unsigned u = __float_as_uint(x);
  u += 0x7FFFu + ((u>>16)&1u);
  return (unsigned short)(u>>16);
}

// ---------------- zero init ----------------
__global__ void zero_kernel(float4* __restrict__ p, int n4){
  int i = blockIdx.x*256 + threadIdx.x;
  if(i < n4) p[i] = make_float4(0.f,0.f,0.f,0.f);
}

// ---------------- generic row-gather GEMM (fp32) ----------------
__global__ __launch_bounds__(256) void gemm_rows(
    const float* __restrict__ Atab, const int* __restrict__ tokens, int T,
    const float* __restrict__ Bw, const float* __restrict__ bias,
    float* __restrict__ C, int N, int K)
{
  __shared__ float as[64*20];
  int tid = threadIdx.x;
  int n  = blockIdx.x*256 + tid;
  int m0 = blockIdx.y*16;
  float acc[16];
  #pragma unroll
  for(int r=0;r<16;r++) acc[r]=0.f;

  for(int kc=0; kc<K; kc+=64){
    __syncthreads();
    for(int i=tid; i<16*64; i+=256){
      int mm = i>>6, kk = i&63;
      int m = m0 + mm;
      const float* arow;
      if(tokens){
        int b = m & 31, t = m >> 5;
        arow = Atab + (size_t)tokens[b*T + t]*K;
      } else {
        arow = Atab + (size_t)m*K;
      }
      as[kk*20 + mm] = arow[kc + kk];
    }
    __syncthreads();
    for(int kk=0; kk<64; kk++){
      float bv = Bw[(size_t)(kc+kk)*N + n];
      const float4* ap = (const float4*)(as + kk*20);
      float4 a0 = ap[0], a1 = ap[1], a2 = ap[2], a3 = ap[3];
      acc[0]  += a0.x*bv; acc[1]  += a0.y*bv; acc[2]  += a0.z*bv; acc[3]  += a0.w*bv;
      acc[4]  += a1.x*bv; acc[5]  += a1.y*bv; acc[6]  += a1.z*bv; acc[7]  += a1.w*bv;
      acc[8]  += a2.x*bv; acc[9]  += a2.y*bv; acc[10] += a2.z*bv; acc[11] += a2.w*bv;
      acc[12] += a3.x*bv; acc[13] += a3.y*bv; acc[14] += a3.z*bv; acc[15] += a3.w*bv;
    }
  }
  float bv = bias ? bias[n] : 0.f;
  #pragma unroll
  for(int r=0;r<16;r++)
    C[(size_t)(m0+r)*N + n] = acc[r] + bv;
}

// ---------------- recurrent-step split-K GEMM (high-MLP) ----------------
// zpart[kq][m][n] = sum_{k in chunk} src[m][k] * W[k][n]
// K chunks of 128: kq<HQ -> (W1, s1, k0=kq*128), else (W2, s2, k0=(kq-HQ)*128).
// block 256 = 4 waves (8 m-rows each) x 64 n. Inner loop unrolled by 16:
// 16 W loads (256B/wave each) issued before the FMA block -> 4KB in
// flight per wave. src reads are wave-uniform float4 (L1 broadcast).
__global__ __launch_bounds__(256) void step_mm(
    const float* __restrict__ W1, const float* __restrict__ W2,
    const float* __restrict__ s1, const float* __restrict__ s2,
    float* __restrict__ zpart, int N, int HQ)
{
  int tid = threadIdx.x;
  int lane = tid & 63, mg = tid >> 6;
  int n = blockIdx.x*64 + lane;
  int kq = blockIdx.y;
  const float* W;
  const float* hp;
  if(kq < HQ){
    int k0 = kq*128;
    W  = W1 + (size_t)k0*N + n;
    hp = s1 + (size_t)(mg*8)*U_ + k0;
  } else {
    int k0 = (kq-HQ)*128;
    W  = W2 + (size_t)k0*N + n;
    hp = s2 + (size_t)(mg*8)*U_ + k0;
  }
  float acc[8];
  #pragma unroll
  for(int i=0;i<8;i++) acc[i]=0.f;

  for(int kk=0; kk<128; kk+=16){
    float w[16];
    #pragma unroll
    for(int j=0;j<16;j++) w[j] = W[(size_t)(kk+j)*N];
    #pragma unroll
    for(int mi=0; mi<8; mi++){
      const float4* h4 = (const float4*)(hp + (size_t)mi*U_ + kk);
      float4 ha = h4[0], hb = h4[1], hc = h4[2], hd = h4[3];
      acc[mi] += ha.x*w[0]  + ha.y*w[1]  + ha.z*w[2]  + ha.w*w[3]
               + hb.x*w[4]  + hb.y*w[5]  + hb.z*w[6]  + hb.w*w[7]
               + hc.x*w[8]  + hc.y*w[9]  + hc.z*w[10] + hc.w*w[11]
               + hd.x*w[12] + hd.y*w[13] + hd.z*w[14] + hd.w*w[15];
    }
  }
  float* zp = zpart + ((size_t)(kq*32 + mg*8)) * N + n;
  #pragma unroll
  for(int mi=0; mi<8; mi++)
    zp[(size_t)mi * N] = acc[mi];
}

// ---------------- gates (encoder; generic partial count) ----------------
__global__ __launch_bounds__(256) void gate_h(
    const float* __restrict__ X_t, const float* __restrict__ zpart, int KQ,
    float* __restrict__ c, float* __restrict__ hout)
{
  int i = blockIdx.x*256 + threadIdx.x;   // 0..32767
  int b = i >> 10, u = i & 1023;
  float zg[4];
  #pragma unroll
  for(int g=0; g<4; g++){
    int col = g*U_ + u;
    float s = X_t[(size_t)b*G_ + col];
    for(int p=0; p<KQ; p++) s += zpart[((size_t)(p*32+b))*G_ + col];
    zg[g] = s;
  }
  float cn = sigf(zg[1])*c[i] + sigf(zg[0])*tanh_fast(zg[2]);
  float hn = sigf(zg[3])*tanh_fast(cn);
  c[i] = cn;
  hout[i] = hn;
}

// ---------------- decoder: gates + scores + softmax + context ----------------
// one block per batch b (32 blocks, 256 threads); 16 z-partials
__global__ __launch_bounds__(256) void dec_gate_attn(
    const float* __restrict__ Xd_t, const float* __restrict__ zpart,
    float* __restrict__ c, const float* __restrict__ keys,
    const float* __restrict__ memory, float* __restrict__ hout,
    float* __restrict__ ctx)
{
  int b = blockIdx.x;
  int tid = threadIdx.x;
  __shared__ float hs[1024];
  __shared__ float sc[64];
  __shared__ float al[64];
  #pragma unroll
  for(int uu=0; uu<4; uu++){
    int u = uu*256 + tid;
    float zg[4];
    #pragma unroll
    for(int g=0; g<4; g++){
      int col = g*U_ + u;
      float s = Xd_t[(size_t)b*G_ + col];
      #pragma unroll
      for(int p=0; p<16; p++) s += zpart[((size_t)(p*32+b))*G_ + col];
      zg[g] = s;
    }
    int ci = b*U_ + u;
    float cn = sigf(zg[1])*c[ci] + sigf(zg[0])*tanh_fast(zg[2]);
    float hn = sigf(zg[3])*tanh_fast(cn);
    c[ci] = cn;
    hs[u] = hn;
    hout[ci] = hn;
  }
  __syncthreads();
  int w = tid>>6, lane = tid&63;
  for(int si=0; si<16; si++){
    int s = w*16 + si;
    const float* kr = keys + ((size_t)s*B_ + b)*U_;
    float p = 0.f;
    for(int kk=lane; kk<1024; kk+=64) p += hs[kk]*kr[kk];
    for(int off=32; off; off>>=1) p += __shfl_down(p, off);
    if(lane==0) sc[s] = p;
  }
  __syncthreads();
  if(tid<64){
    float v = sc[tid];
    float mx = v;
    for(int off=32; off; off>>=1) mx = fmaxf(mx, __shfl_down(mx, off));
    mx = __shfl(mx, 0);
    float e = __expf(v - mx);
    float sm = e;
    for(int off=32; off; off>>=1) sm += __shfl_down(sm, off);
    sm = __shfl(sm, 0);
    al[tid] = e/sm;
  }
  __syncthreads();
  #pragma unroll
  for(int uu=0; uu<4; uu++){
    int u = uu*256 + tid;
    float a = 0.f;
    for(int s=0; s<64; s++) a += al[s]*memory[((size_t)s*B_ + b)*U_ + u];
    ctx[b*U_ + u] = a;
  }
}

// ---------------- attention-projection combine (+bf16 emit) ----------------
__global__ __launch_bounds__(256) void attn_combine(
    const float* __restrict__ apart, float* __restrict__ attn_next,
    unsigned short* __restrict__ abf)
{
  int i = blockIdx.x*256 + threadIdx.x;   // 0..32767
  float s = 0.f;
  #pragma unroll
  for(int p=0; p<16; p++) s += apart[(size_t)p*32768 + i];
  attn_next[i] = s;
  abf[i] = f2bf(s);
}

// Wf [1024][32000] f32 -> WfT [32000][1024] bf16
__global__ __launch_bounds__(256) void transpose_f2bf(
    const float* __restrict__ Wf, unsigned short* __restrict__ WfT)
{
  __shared__ float t[32][33];
  int n0 = blockIdx.x*32, k0 = blockIdx.y*32;
  int tid = threadIdx.x;
  int cx = tid&31, ry = tid>>5;
  for(int r=ry; r<32; r+=8) t[r][cx] = Wf[(size_t)(k0+r)*VT_ + n0+cx];
  __syncthreads();
  for(int r=ry; r<32; r+=8)
    WfT[(size_t)(n0+r)*1024 + k0+cx] = f2bf(t[cx][r]);
}

// ---------------- logits GEMM: bf16 MFMA 16x16x32 ----------------
__global__ __launch_bounds__(256) void logits_gemm(
    const unsigned short* __restrict__ Abf, const unsigned short* __restrict__ Bt,
    const float* __restrict__ bias, float* __restrict__ out)
{
  __shared__ __align__(16) unsigned short As[32][40];
  __shared__ __align__(16) unsigned short Bs[256][40];
  int tid = threadIdx.x;
  int m0 = blockIdx.x*32, n0 = blockIdx.y*256;
  int w = tid>>6, lane = tid&63;
  int wm = w&1, wn = w>>1;
  floatx4 acc[8];
  #pragma unroll
  for(int i=0;i<8;i++) acc[i] = (floatx4)(0.f);

  int rl = lane&15, kg = lane>>4;

  for(int kt=0; kt<1024; kt+=32){
    __syncthreads();
    {
      int mm = tid>>3, kq = tid&7;
      const unsigned short* src = Abf + (size_t)(m0+mm)*1024 + kt + kq*4;
      *(uint2*)(&As[mm][kq*4]) = *(const uint2*)src;
    }
    {
      const unsigned short* bsrc = Bt + (size_t)(n0+tid)*1024 + kt;
      *(uint4*)(&Bs[tid][0])  = *(const uint4*)(bsrc);
      *(uint4*)(&Bs[tid][8])  = *(const uint4*)(bsrc+8);
      *(uint4*)(&Bs[tid][16]) = *(const uint4*)(bsrc+16);
      *(uint4*)(&Bs[tid][24]) = *(const uint4*)(bsrc+24);
    }
    __syncthreads();
    short8 afrag = *(const short8*)(&As[wm*16 + rl][kg*8]);
    #pragma unroll
    for(int nt=0; nt<8; nt++){
      short8 bfrag = *(const short8*)(&Bs[wn*128 + nt*16 + rl][kg*8]);
      acc[nt] = __builtin_amdgcn_mfma_f32_16x16x32_bf16(afrag, bfrag, acc[nt], 0,0,0);
    }
  }
  #pragma unroll
  for(int nt=0; nt<8; nt++){
    int n = n0 + wn*128 + nt*16 + rl;
    float bv = bias[n];
    #pragma unroll
    for(int r=0;r<4;r++){
      int m = m0 + wm*16 + kg*4 + r;
      int t = m>>5, b = m&31;
      out[((size_t)(b*TD_) + t)*VT_ + n] = acc[nt][r] + bv;
    }
  }
}

// ---------------- host ----------------
extern "C" void kernel_launch(void* const* d_in, const int* in_sizes, int n_in,
                              void* d_out, int out_size, void* d_ws, size_t ws_size,
                              hipStream_t stream) {
  (void)in_sizes; (void)n_in; (void)out_size; (void)ws_size;
  const int*   enc_in  = (const int*)d_in[0];
  const int*   dec_in  = (const int*)d_in[1];
  const float* enc_emb = (const float*)d_in[2];
  const float* dec_emb = (const float*)d_in[3];
  const float* Wx_e    = (const float*)d_in[4];
  const float* Wh_e    = (const float*)d_in[5];
  const float* b_e     = (const float*)d_in[6];
  const float* Wx_d    = (const float*)d_in[7];
  const float* Wh_d    = (const float*)d_in[8];
  const float* b_d     = (const float*)d_in[9];
  const float* Wm      = (const float*)d_in[10];
  const float* Wa      = (const float*)d_in[11];
  const float* Wf      = (const float*)d_in[12];
  const float* bf      = (const float*)d_in[13];
  float* out = (float*)d_out;

  float* ws = (float*)d_ws;
  size_t off = 0;
  float* Xe       = ws + off; off += (size_t)TS_*B_*G_;     // 8388608
  float* Xd       = ws + off; off += (size_t)TD_*B_*G_;     // 8257536
  float* memory   = ws + off; off += (size_t)TS_*B_*U_;     // 2097152
  float* keys     = ws + off; off += (size_t)TS_*B_*U_;     // 2097152
  float* attn_buf = ws + off; off += (size_t)64*B_*U_;      // slot0 = zeros
  float* cbuf     = ws + off; off += (size_t)B_*U_;
  float* hbuf     = ws + off; off += (size_t)B_*U_;
  float* ctx      = ws + off; off += (size_t)B_*U_;
  float* zpart    = ws + off; off += (size_t)16*B_*G_;      // 16 split-K slots
  float* apart    = ws + off; off += (size_t)16*B_*U_;      // 16 split-K slots
  unsigned short* attn_bf = (unsigned short*)(ws + off); off += (size_t)(2016*1024)/2;
  unsigned short* WfT     = (unsigned short*)(ws + off);

  // zero attn slot0 + cbuf
  zero_kernel<<<32, 256, 0, stream>>>((float4*)attn_buf, (B_*U_)/4);
  zero_kernel<<<32, 256, 0, stream>>>((float4*)cbuf, (B_*U_)/4);

  // input pre-activations + Wf transpose (off the critical recurrence)
  gemm_rows<<<dim3(G_/256, (TS_*B_)/16), 256, 0, stream>>>(enc_emb, enc_in, TS_, Wx_e, b_e, Xe, G_, E_);
  gemm_rows<<<dim3(G_/256, (TD_*B_)/16), 256, 0, stream>>>(dec_emb, dec_in, TD_, Wx_d, b_d, Xd, G_, E_);
  transpose_f2bf<<<dim3(VT_/32, 1024/32), 256, 0, stream>>>(Wf, WfT);

  // encoder recurrence: z = h@Wh_e (split-K 8 x 128), then gates
  for(int t=0; t<TS_; t++){
    const float* hprev = (t==0) ? attn_buf : memory + (size_t)(t-1)*B_*U_;
    step_mm<<<dim3(G_/64, 8), 256, 0, stream>>>(Wh_e, Wh_e, hprev, hprev, zpart, G_, 8);
    gate_h<<<128, 256, 0, stream>>>(Xe + (size_t)t*B_*G_, zpart, 8, cbuf,
                                    memory + (size_t)t*B_*U_);
  }

  // keys = memory @ Wm
  gemm_rows<<<dim3(U_/256, (TS_*B_)/16), 256, 0, stream>>>(memory, nullptr, 0, Wm, nullptr, keys, U_, U_);

  // decoder recurrence
  const float* mem_last = memory + (size_t)(TS_-1)*B_*U_;
  const float* Wxa = Wx_d + (size_t)E_*G_;
  const float* Wa2 = Wa + (size_t)U_*U_;
  for(int t=0; t<TD_; t++){
    const float* hin   = (t==0) ? mem_last : hbuf;
    const float* aprev = attn_buf + (size_t)t*B_*U_;
    float* anext       = attn_buf + (size_t)(t+1)*B_*U_;
    // z = h@Wh_d + a@Wxa (split-K 16 x 128)
    step_mm<<<dim3(G_/64, 16), 256, 0, stream>>>(Wh_d, Wxa, hin, aprev, zpart, G_, 8);
    // gates + scores + softmax + context
    dec_gate_attn<<<B_, 256, 0, stream>>>(Xd + (size_t)t*B_*G_, zpart, cbuf,
                                          keys, memory, hbuf, ctx);
    // attn = [h|ctx] @ Wa (split-K 16 x 128)
    step_mm<<<dim3(U_/64, 16), 256, 0, stream>>>(Wa, Wa2, hbuf, ctx, apart, U_, 8);
    attn_combine<<<128, 256, 0, stream>>>(apart, anext, attn_bf + (size_t)t*B_*U_);
  }

  // logits = attn_all @ Wf + bf  (bf16 MFMA)
  logits_gemm<<<dim3((TD_*B_)/32, VT_/256), 256, 0, stream>>>(attn_bf, WfT, bf, out);
}